// Round 6
// baseline (158.785 us; speedup 1.0000x reference)
//
#include <hip/hip_runtime.h>
#include <stdint.h>

typedef __attribute__((ext_vector_type(8))) short short8;
typedef __attribute__((ext_vector_type(4))) float f32x4;
typedef __attribute__((ext_vector_type(8))) float f32x8;
typedef __bf16 bf16x8_t __attribute__((ext_vector_type(8)));

#define NN     784             // 28*28
#define BM     64              // images per block
#define NA     28              // output rows (a)
#define NSLOT  8               // K-slots of 32 per a (256-wide window covers the 196 band)
#define FRAG_U16 512           // ushorts per 16x32 B-fragment
#define ABYTES  (NSLOT * 2 * FRAG_U16 * 2)   // 16384 B of B-table per a

__device__ __forceinline__ unsigned short f2bf(float f) {
  unsigned int u = __float_as_uint(f);
  return (unsigned short)((u + 0x7FFFu + ((u >> 16) & 1u)) >> 16);  // RNE, finite inputs
}

__device__ __forceinline__ short8 cvt8(f32x4 lo, f32x4 hi) {
  f32x8 f = {lo.x, lo.y, lo.z, lo.w, hi.x, hi.y, hi.z, hi.w};
  bf16x8_t b = __builtin_convertvector(f, bf16x8_t);   // v_cvt_pk_bf16_f32 (RNE)
  return __builtin_bit_cast(short8, b);
}

// First stored k-slot for output row a: 32-aligned window start covering
// k in [28(a-3), 28(a+4)), clamped so slots s=0..7 stay in [0,24].
__device__ __forceinline__ int slot0(int a) {
  int t = 28 * a - 84;
  if (t < 0) t = 0;
  t >>= 5;
  if (t > 17) t = 17;
  return t;
}

// Bpack[a][s][nf] = 1KB MFMA W-fragment (16 outcols x 32 k), frag-contiguous.
// In-frag u16 index for (outcol rl, k kk): ((kk>>3)*16 + rl)*8 + (kk&7).
// Value = weight[a*28+ncol] * W[a*28+ncol][kglob], 0 outside grid/band.
__global__ void build_w_kernel(const float* __restrict__ pos2d,
                               const float* __restrict__ weight,
                               const float* __restrict__ ep,
                               unsigned short* __restrict__ Bpack) {
  int idx = blockIdx.x * 256 + threadIdx.x;   // 0 .. 28*8*2*512-1
  int u    = idx & 511;
  int frag = idx >> 9;          // ((a*8 + s)*2 + nf)
  int nf = frag & 1;
  int s  = (frag >> 1) & 7;
  int a  = frag >> 4;
  int j8   = u & 7;
  int lane = u >> 3;
  int rl = lane & 15;
  int ch = lane >> 4;
  int kk = ch * 8 + j8;                        // 0..31
  int kglob = (slot0(a) + s) * 32 + kk;
  int ncol  = nf * 16 + rl;
  float val = 0.f;
  if (ncol < 28 && kglob < NN) {
    float px = pos2d[2 * kglob + 0];
    float py = pos2d[2 * kglob + 1];
    float dx = (float)ncol - px;
    float dy = (float)a - py;
    float d2 = __fadd_rn(__fmul_rn(dx, dx), __fmul_rn(dy, dy));  // match np (no fma)
    if (d2 < 9.0f) {
      float en = fminf(ep[kglob], 0.f);
      val = expf(en * d2) * weight[a * 28 + ncol];
    }
  }
  Bpack[idx] = f2bf(val);
}

// Banded GEMM, pipelined: 3-deep LDS ring for the 16KB per-a W-tile, one raw
// s_barrier + counted vmcnt per iteration (stores + next stage stay in flight).
// Swapped MFMA operands (W as A, x as B) -> C[outcol, image] -> dwordx4 stores.
__global__ __launch_bounds__(256, 3)
void gemm_kernel(const float* __restrict__ x,
                 const unsigned short* __restrict__ Bpack,
                 float* __restrict__ out) {
  __shared__ unsigned short Blds[3][NSLOT * 2 * FRAG_U16];   // 3 x 16 KB

  const int tid  = threadIdx.x;
  const int wave = tid >> 6;
  const int lane = tid & 63;
  const int rl   = lane & 15;       // image slot / W-frag outcol
  const int ch   = lane >> 4;       // k-chunk of 8
  const int m0   = blockIdx.x * BM;

  auto stage = [&](int buf, int a) {
    const char* src = (const char*)Bpack + (size_t)a * ABYTES + tid * 16;
    char* dst = (char*)&Blds[buf][0] + tid * 16;
    #pragma unroll
    for (int i = 0; i < 4; ++i)
      __builtin_amdgcn_global_load_lds(
          (const __attribute__((address_space(1))) uint32_t*)(src + i * 4096),
          (__attribute__((address_space(3))) uint32_t*)(uintptr_t)(dst + i * 4096),
          16, 0, 0);
  };

  stage(0, 0);    // oldest VMEM ops; iter 0 uses vmcnt(0) so ordering vs x-loads is moot

  // Lane's x row (image m0 + wave*16 + rl), k-phase ch, into 25 short8s (bf16).
  const float* xrow = x + (size_t)(m0 + wave * 16 + rl) * NN;
  short8 xr[25];
  #pragma unroll
  for (int t = 0; t < 25; ++t) {
    int k = t * 32 + ch * 8;
    f32x4 lo = (f32x4){0.f, 0.f, 0.f, 0.f};
    f32x4 hi = (f32x4){0.f, 0.f, 0.f, 0.f};
    if (k + 7 < NN) {                 // tail chunks (k>776) are 0; W pad is 0 too
      lo = *(const f32x4*)(xrow + k);
      hi = *(const f32x4*)(xrow + k + 4);
    }
    xr[t] = cvt8(lo, hi);
  }
  stage(1, 1);
  __builtin_amdgcn_sched_barrier(0);

  const char* lds0 = (const char*)&Blds[0][0];
  float* orow = out + (size_t)(m0 + wave * 16 + rl) * NN;

  #pragma unroll
  for (int a = 0; a < NA; ++a) {
    // Wait for stage(a) to have landed in LDS (in-order VMEM retirement):
    // steady state: newer-than-stage(a) = stores(a-2)[2] + stage(a+1)[4] + stores(a-1)[2] = 8.
    if (a == 0)           asm volatile("s_waitcnt vmcnt(0)" ::: "memory");
    else if (a == NA - 1) asm volatile("s_waitcnt vmcnt(4)" ::: "memory");
    else                  asm volatile("s_waitcnt vmcnt(8)" ::: "memory");
    __builtin_amdgcn_sched_barrier(0);
    __builtin_amdgcn_s_barrier();          // all waves: stage(a) visible, buf[(a+2)%3] free
    __builtin_amdgcn_sched_barrier(0);
    if (a + 2 < NA) stage((a + 2) % 3, a + 2);
    __builtin_amdgcn_sched_barrier(0);

    const char* buf = lds0 + (size_t)(a % 3) * (NSLOT * 2 * FRAG_U16 * 2);
    const int t0 = slot0(a);               // compile-time (a is unrolled)
    f32x4 acc0 = (f32x4){0.f, 0.f, 0.f, 0.f};
    f32x4 acc1 = (f32x4){0.f, 0.f, 0.f, 0.f};

    #pragma unroll
    for (int s = 0; s < NSLOT; ++s) {
      short8 w0 = *(const short8*)(buf + (s * 2 + 0) * 1024 + lane * 16);
      short8 w1 = *(const short8*)(buf + (s * 2 + 1) * 1024 + lane * 16);
      short8 xf = xr[t0 + s];
      acc0 = __builtin_amdgcn_mfma_f32_16x16x32_bf16(w0, xf, acc0, 0, 0, 0);
      acc1 = __builtin_amdgcn_mfma_f32_16x16x32_bf16(w1, xf, acc1, 0, 0, 0);
    }

    // C'[r=outcol, c=image]: lane holds image rl, outcols ch*4+{0..3} (+16 for acc1).
    float* op = orow + a * 28 + ch * 4;
    *(f32x4*)op = acc0;                      // global_store_dwordx4
    if (ch < 3) *(f32x4*)(op + 16) = acc1;   // outcols 16..27 only
    __builtin_amdgcn_sched_barrier(0);
  }
}

extern "C" void kernel_launch(void* const* d_in, const int* in_sizes, int n_in,
                              void* d_out, int out_size, void* d_ws, size_t ws_size,
                              hipStream_t stream) {
  const float* x      = (const float*)d_in[0];
  const float* pos2d  = (const float*)d_in[1];
  const float* weight = (const float*)d_in[2];
  const float* ep     = (const float*)d_in[3];
  float* out          = (float*)d_out;
  unsigned short* Bpack = (unsigned short*)d_ws;        // 28*8*2*512*2 = 458,752 B

  int batch = in_sizes[0] / NN;                         // 65536

  build_w_kernel<<<dim3((NA * NSLOT * 2 * FRAG_U16) / 256), dim3(256), 0, stream>>>(
      pos2d, weight, ep, Bpack);
  gemm_kernel<<<dim3(batch / BM), dim3(256), 0, stream>>>(x, Bpack, out);
}

// Round 7
// 157.757 us; speedup vs baseline: 1.0065x; 1.0065x over previous
//
#include <hip/hip_runtime.h>
#include <stdint.h>

typedef __attribute__((ext_vector_type(8))) short short8;
typedef __attribute__((ext_vector_type(4))) float f32x4;
typedef __attribute__((ext_vector_type(8))) float f32x8;
typedef __bf16 bf16x8_t __attribute__((ext_vector_type(8)));

#define NN     784             // 28*28
#define BM     64              // images per block
#define NA     28              // output rows (a)
#define NSLOT  8               // K-slots of 32 per a (256-wide window covers the 196 band)
#define FRAG_U16 512           // ushorts per 16x32 W-fragment
#define ABYTES  (NSLOT * 2 * FRAG_U16 * 2)   // 16384 B of W-table per a
#define TILE_B  16384

__device__ __forceinline__ unsigned short f2bf(float f) {
  unsigned int u = __float_as_uint(f);
  return (unsigned short)((u + 0x7FFFu + ((u >> 16) & 1u)) >> 16);  // RNE, finite inputs
}

__device__ __forceinline__ short8 cvt8(f32x4 lo, f32x4 hi) {
  f32x8 f = {lo.x, lo.y, lo.z, lo.w, hi.x, hi.y, hi.z, hi.w};
  bf16x8_t b = __builtin_convertvector(f, bf16x8_t);   // v_cvt_pk_bf16_f32 (RNE)
  return __builtin_bit_cast(short8, b);
}

// First stored k-slot for output row a: 32-aligned window start covering
// k in [28(a-3), 28(a+4)), clamped so slots s=0..7 stay in [0,24].
__host__ __device__ constexpr int slot0c(int a) {
  int t = 28 * a - 84;
  if (t < 0) t = 0;
  t >>= 5;
  if (t > 17) t = 17;
  return t;
}

// Bpack[a][s][nf] = 1KB MFMA W-fragment (16 outcols x 32 k), frag-contiguous.
// In-frag u16 index for (outcol rl, k kk): ((kk>>3)*16 + rl)*8 + (kk&7).
// Value = weight[a*28+ncol] * W[a*28+ncol][kglob], 0 outside grid/band.
__global__ void build_w_kernel(const float* __restrict__ pos2d,
                               const float* __restrict__ weight,
                               const float* __restrict__ ep,
                               unsigned short* __restrict__ Bpack) {
  int idx = blockIdx.x * 256 + threadIdx.x;   // 0 .. 28*8*2*512-1
  int u    = idx & 511;
  int frag = idx >> 9;          // ((a*8 + s)*2 + nf)
  int nf = frag & 1;
  int s  = (frag >> 1) & 7;
  int a  = frag >> 4;
  int j8   = u & 7;
  int lane = u >> 3;
  int rl = lane & 15;
  int ch = lane >> 4;
  int kk = ch * 8 + j8;                        // 0..31
  int kglob = (slot0c(a) + s) * 32 + kk;
  int ncol  = nf * 16 + rl;
  float val = 0.f;
  if (ncol < 28 && kglob < NN) {
    float px = pos2d[2 * kglob + 0];
    float py = pos2d[2 * kglob + 1];
    float dx = (float)ncol - px;
    float dy = (float)a - py;
    float d2 = __fadd_rn(__fmul_rn(dx, dx), __fmul_rn(dy, dy));  // match np (no fma)
    if (d2 < 9.0f) {
      float en = fminf(ep[kglob], 0.f);
      val = expf(en * d2) * weight[a * 28 + ncol];
    }
  }
  Bpack[idx] = f2bf(val);
}

__device__ __forceinline__ void stage_tile(const unsigned short* Bpack, char* lds,
                                           int buf, int a, int tid) {
  const char* src = (const char*)Bpack + (size_t)a * ABYTES + tid * 16;
  char* dst = lds + buf * TILE_B + tid * 16;
  #pragma unroll
  for (int i = 0; i < 4; ++i)
    __builtin_amdgcn_global_load_lds(
        (const __attribute__((address_space(1))) uint32_t*)(src + i * 4096),
        (__attribute__((address_space(3))) uint32_t*)(uintptr_t)(dst + i * 4096),
        16, 0, 0);
}

// Compile-time-unrolled per-a iteration: A is a template parameter so the
// x-register window index slot0c(A)+s is STATIC -> xr stays in registers
// (runtime-indexed ext_vector arrays go to scratch -- that was R5/R6's stall).
template <int A>
struct Iter {
  static __device__ __forceinline__ void run(const short8 (&xr)[25],
                                             const unsigned short* Bpack,
                                             char* lds, int tid, int lane,
                                             float* orow) {
    // Wait for stage(A) to have landed (in-order VMEM retirement):
    // steady state: newer-than-stage(A) = stores(A-2)[2] + stage(A+1)[4] + stores(A-1)[2] = 8.
    if constexpr (A == 0)            { asm volatile("s_waitcnt vmcnt(0)" ::: "memory"); }
    else if constexpr (A == NA - 1)  { asm volatile("s_waitcnt vmcnt(4)" ::: "memory"); }
    else                             { asm volatile("s_waitcnt vmcnt(8)" ::: "memory"); }
    __builtin_amdgcn_sched_barrier(0);
    __builtin_amdgcn_s_barrier();          // stage(A) visible, buf[(A+2)%3] free
    __builtin_amdgcn_sched_barrier(0);
    if constexpr (A + 2 < NA) stage_tile(Bpack, lds, (A + 2) % 3, A + 2, tid);
    __builtin_amdgcn_sched_barrier(0);

    const char* buf = lds + (A % 3) * TILE_B;
    constexpr int T0 = slot0c(A);
    f32x4 acc0 = (f32x4){0.f, 0.f, 0.f, 0.f};
    f32x4 acc1 = (f32x4){0.f, 0.f, 0.f, 0.f};

    #pragma unroll
    for (int s = 0; s < NSLOT; ++s) {
      short8 w0 = *(const short8*)(buf + (s * 2 + 0) * 1024 + lane * 16);
      short8 w1 = *(const short8*)(buf + (s * 2 + 1) * 1024 + lane * 16);
      short8 xf = xr[T0 + s];                            // STATIC index
      acc0 = __builtin_amdgcn_mfma_f32_16x16x32_bf16(w0, xf, acc0, 0, 0, 0);
      acc1 = __builtin_amdgcn_mfma_f32_16x16x32_bf16(w1, xf, acc1, 0, 0, 0);
    }

    // C'[r=outcol, c=image]: lane holds image rl, outcols ch*4+{0..3} (+16 for acc1).
    const int ch = lane >> 4;
    float* op = orow + A * 28 + ch * 4;
    *(f32x4*)op = acc0;                      // global_store_dwordx4
    if (ch < 3) *(f32x4*)(op + 16) = acc1;   // outcols 16..27 only
    __builtin_amdgcn_sched_barrier(0);

    Iter<A + 1>::run(xr, Bpack, lds, tid, lane, orow);
  }
};
template <>
struct Iter<NA> {
  static __device__ __forceinline__ void run(const short8 (&)[25],
                                             const unsigned short*, char*, int,
                                             int, float*) {}
};

// Banded GEMM: out[b, a*28+c] = sum_k x[b,k] * W[a*28+c, k], k in a 256-window.
// 4 waves x 16 images; each lane keeps its whole x row in registers (bf16);
// W-tile (16KB per a) in a 3-deep LDS ring via global_load_lds; one raw
// s_barrier + counted vmcnt per iteration; swapped MFMA operands (W as A,
// x as B) -> C[outcol, image] -> contiguous dwordx4 stores per image.
__global__ __launch_bounds__(256, 3)
void gemm_kernel(const float* __restrict__ x,
                 const unsigned short* __restrict__ Bpack,
                 float* __restrict__ out) {
  __shared__ unsigned short Blds[3][NSLOT * 2 * FRAG_U16];   // 3 x 16 KB

  const int tid  = threadIdx.x;
  const int wave = tid >> 6;
  const int lane = tid & 63;
  const int rl   = lane & 15;       // image slot / W-frag outcol
  const int ch   = lane >> 4;       // k-chunk of 8
  const int m0   = blockIdx.x * BM;
  char* lds = (char*)&Blds[0][0];

  stage_tile(Bpack, lds, 0, 0, tid);   // oldest VMEM ops

  // Lane's x row (image m0 + wave*16 + rl), k-phase ch, into 25 short8s (bf16).
  const float* xrow = x + (size_t)(m0 + wave * 16 + rl) * NN;
  short8 xr[25];
  #pragma unroll
  for (int t = 0; t < 25; ++t) {
    int k = t * 32 + ch * 8;
    f32x4 lo = (f32x4){0.f, 0.f, 0.f, 0.f};
    f32x4 hi = (f32x4){0.f, 0.f, 0.f, 0.f};
    if (k + 7 < NN) {                 // tail chunks (k>783) are 0; W pad is 0 too
      lo = *(const f32x4*)(xrow + k);
      hi = *(const f32x4*)(xrow + k + 4);
    }
    xr[t] = cvt8(lo, hi);
  }
  stage_tile(Bpack, lds, 1, 1, tid);
  __builtin_amdgcn_sched_barrier(0);

  float* orow = out + (size_t)(m0 + wave * 16 + rl) * NN;
  Iter<0>::run(xr, Bpack, lds, tid, lane, orow);
}

extern "C" void kernel_launch(void* const* d_in, const int* in_sizes, int n_in,
                              void* d_out, int out_size, void* d_ws, size_t ws_size,
                              hipStream_t stream) {
  const float* x      = (const float*)d_in[0];
  const float* pos2d  = (const float*)d_in[1];
  const float* weight = (const float*)d_in[2];
  const float* ep     = (const float*)d_in[3];
  float* out          = (float*)d_out;
  unsigned short* Bpack = (unsigned short*)d_ws;        // 28*8*2*512*2 = 458,752 B

  int batch = in_sizes[0] / NN;                         // 65536

  build_w_kernel<<<dim3((NA * NSLOT * 2 * FRAG_U16) / 256), dim3(256), 0, stream>>>(
      pos2d, weight, ep, Bpack);
  gemm_kernel<<<dim3(batch / BM), dim3(256), 0, stream>>>(x, Bpack, out);
}